// Round 22
// baseline (41.549 us; speedup 1.0000x reference)
//
#include <hip/hip_runtime.h>
#include <rocwmma/rocwmma.hpp>
#include <cstddef>

#define NT 10            // NUM_TOKENS
#define TD 96            // TOKEN_DIM == REF_DIM
#define NH 4             // NUM_HEADS
#define NPOS (32 * 2048) // B*T positions
#define TPB 256
#define PPB 32           // positions per block; 8 per wave, end-to-end
#define LDQ 104          // padded f16 leading dim of each wave slice

// workspace layout (bytes)
#define WS_WQ 0          // f16 wq16[96][96] row-major (18432 B) -> wmma B
#define WS_KV2 18432     // float Ek[96][12]: e^{2 tanh(tok.Wk)}, pad 2 (4608 B)
#define WS_WVP 23040     // h2 wvp[6][8][4]: (Wv[h][16pp+l], Wv[h][16pp+8+l]) (768 B)
#define WS_C 23808       // float C[4]: C[h] = sum_d Wv[h][d] (16 B)
#define WS_BYTES 23824

typedef _Float16 h2 __attribute__((ext_vector_type(2)));

__device__ __forceinline__ h2 pack_h2(float a, float b) {
    return __builtin_bit_cast(h2, __builtin_amdgcn_cvt_pkrtz(a, b));
}

__device__ __forceinline__ float fast_tanh(float x) {
    // tanh(x) = 1 - 2/(exp(2x)+1); exact limits at +/-inf, ~1e-6 rel error
    float e = __expf(2.0f * x);
    return 1.0f - 2.0f * __builtin_amdgcn_rcpf(e + 1.0f);
}

__device__ __forceinline__ float dot2acc(h2 a, h2 b, float c) {
#if __has_builtin(__builtin_amdgcn_fdot2)
    return __builtin_amdgcn_fdot2(a, b, c, false);
#else
    c = fmaf((float)a[0], (float)b[0], c);
    return fmaf((float)a[1], (float)b[1], c);
#endif
}

// ---- prep: 48 blocks; block b owns d-slice [2b, 2b+2); block 0 also wvp/C ----
__global__ __launch_bounds__(256) void gst_prep(
    const float* __restrict__ tokens,
    const float* __restrict__ Wq,
    const float* __restrict__ Wk,
    const float* __restrict__ Wv,
    char* __restrict__ ws)
{
    h2* wqH = (h2*)(ws + WS_WQ);
    float* kv2 = (float*)(ws + WS_KV2);
    h2* wvp = (h2*)(ws + WS_WVP);
    float* Cws = (float*)(ws + WS_C);
    const int b = blockIdx.x;
    const int tid = threadIdx.x;

    // Wq rows -> f16 (2 rows x 48 pairs); [96][48] h2 == [96][96] f16 row-major
    if (tid < 2 * (TD / 2)) {
        int r = 2 * b + tid / (TD / 2);
        int c = tid % (TD / 2);
        float2 f = ((const float2*)(Wq + r * TD))[c];
        wqH[r * (TD / 2) + c] = pack_h2(f.x, f.y);
    }
    // Ek[d][n] = exp(2 * tanh(tokens[n] . Wk[d]))   (exp-form of tanh addition)
    if (tid < 2 * NT) {
        int d = 2 * b + tid / NT;
        int n = tid % NT;
        const float4* tr = (const float4*)(tokens + n * TD);
        const float4* wr = (const float4*)(Wk + d * TD);
        float acc = 0.0f;
        #pragma unroll
        for (int j = 0; j < TD / 4; ++j) {
            float4 a = tr[j];
            float4 w = wr[j];
            acc = fmaf(a.x, w.x, acc);
            acc = fmaf(a.y, w.y, acc);
            acc = fmaf(a.z, w.z, acc);
            acc = fmaf(a.w, w.w, acc);
        }
        kv2[d * 12 + n] = __expf(2.0f * fast_tanh(acc));
    }
    if (tid < 2 * 2) { // zero the pad
        int d = 2 * b + (tid >> 1);
        kv2[d * 12 + 10 + (tid & 1)] = 0.0f;
    }
    // wvp pairs (block 0): 192 items
    if (b == 0 && tid < 192) {
        int pp = tid >> 5;
        int l = (tid >> 2) & 7;
        int h = tid & 3;
        wvp[(pp * 8 + l) * 4 + h] =
            pack_h2(Wv[h * TD + 16 * pp + l], Wv[h * TD + 16 * pp + 8 + l]);
    }
    // C[h] = sum_d Wv[h][d] (block 0, threads 224..227)
    if (b == 0 && tid >= 224 && tid < 224 + NH) {
        int h = tid - 224;
        float c = 0.0f;
        for (int d = 0; d < TD; ++d) c += Wv[h * TD + d];
        Cws[h] = c;
    }
}

// ---- main: wave-local slices, ONE block barrier. Each wave owns 8 positions
//      end-to-end: x-stage -> fa -> mma -> eq (slice reuse) -> s-phase. ----
__global__ __launch_bounds__(TPB, 6) void gst_main(
    const float* __restrict__ ref_emb,
    const float* __restrict__ tokens,
    const char* __restrict__ ws,
    float* __restrict__ out)
{
    __shared__ __align__(16) _Float16 xS[4 * 8 * LDQ]; // 6656 B: 4 wave slices
    __shared__ __align__(16) float kvS[TD * 12];       // 4608 B: Ek
    __shared__ __align__(16) h2 wvpS[6 * 8 * 4];       //  768 B
    __shared__ __align__(16) float tokS[NT * TD];      // 3840 B (total 15872)

    const int tid = threadIdx.x;
    const int lane = tid & 63;
    const int wid = tid >> 6;
    const int posbase = blockIdx.x * PPB + wid * 8; // this wave's 8 positions
    _Float16* slice = xS + wid * 8 * LDQ;

    // ---- wave-local x-stage: 8 rows x 24 float4 = 192 float4, 3 per lane ----
    {
        const float4* src = (const float4*)(ref_emb + (size_t)posbase * TD);
        #pragma unroll
        for (int j = 0; j < 3; ++j) {
            int idx = lane + 64 * j;
            int row = idx / 24;
            int c4 = idx - row * 24;
            float4 v = src[idx];
            h2* dst = (h2*)(slice + row * LDQ + c4 * 4);
            dst[0] = pack_h2(v.x, v.y);
            dst[1] = pack_h2(v.z, v.w);
        }
    }
    // ---- block-shared staging: kv (288 f4) + wvp (48 f4) + tokens (240 f4) --
    //      full coverage (R21 bug: tokens 192..239 were never staged) ----
    {
        const float4* sKV = (const float4*)(ws + WS_KV2);
        float4* dKV = (float4*)kvS;
        dKV[tid] = sKV[tid];
        if (tid < 32) dKV[256 + tid] = sKV[256 + tid];
        const float4* sWV = (const float4*)(ws + WS_WVP);
        float4* dWV = (float4*)wvpS;
        if (tid < 48) dWV[tid] = sWV[tid];
        if (tid < NT * TD / 4)
            ((float4*)tokS)[tid] = ((const float4*)tokens)[tid];
    }
    __syncthreads(); // the ONLY block barrier

    // ---- wave-local wmma: fa once (rows 8-15 read garbage, discarded);
    //      2 passes x 3 d-tiles; eq overwrites the slice (kgrp<2 guard) ----
    {
        using namespace rocwmma;
        const int arow = lane & 15;
        const int kgrp = lane >> 4;

        fragment<matrix_a, 16, 16, 16, float16_t, row_major> fa[6];
        #pragma unroll
        for (int kb = 0; kb < 6; ++kb)
            load_matrix_sync(fa[kb], (const float16_t*)(slice + kb * 16), LDQ);

        const float16_t* wq16 = (const float16_t*)(ws + WS_WQ);
        #pragma unroll
        for (int pass = 0; pass < 2; ++pass) {
            fragment<accumulator, 16, 16, 16, float> fc[3];
            #pragma unroll
            for (int t = 0; t < 3; ++t) {
                fill_fragment(fc[t], 0.0f);
                #pragma unroll
                for (int kb = 0; kb < 6; ++kb) {
                    fragment<matrix_b, 16, 16, 16, float16_t, col_major> fb;
                    load_matrix_sync(fb,
                        wq16 + (pass * 3 + t) * 16 * TD + kb * 16, TD);
                    mma_sync(fc[t], fa[kb], fb, fc[t]);
                }
            }
            if (kgrp < 2) { // valid positions: p = kgrp*4+e in [0,8)
                #pragma unroll
                for (int t = 0; t < 3; ++t) {
                    const int d = pass * 48 + t * 16 + arow;
                    #pragma unroll
                    for (int e = 0; e < 4; ++e) {
                        const int p = kgrp * 4 + e;
                        slice[p * LDQ + d] =
                            (_Float16)__expf(2.0f * fast_tanh(fc[t].x[e]));
                    }
                }
            }
        }
    }
    // intra-wave LDS ordering (eq writes -> s-phase reads) via lgkmcnt

    // ---- s-phase (exp form): 8 lanes/pos, lane owns d-pair {16pp+l, +8} ----
    const int prow = lane >> 3;           // pos within this wave's 8
    const int pos = posbase + prow;
    const int l = lane & 7;
    const _Float16* eqrow = slice + prow * LDQ;

    float R[NT][NH]; // R[n][h] = sum_d r(n,d) * wv(h,d); logit = C - 2R
    #pragma unroll
    for (int n = 0; n < NT; ++n)
        #pragma unroll
        for (int h = 0; h < NH; ++h) R[n][h] = 0.0f;

    #pragma unroll
    for (int pp = 0; pp < 6; ++pp) {
        const int d1 = 16 * pp + l;
        const float Eq1 = (float)eqrow[d1];
        const float Eq2 = (float)eqrow[d1 + 8];

        const float* r1 = kvS + d1 * 12;
        const float* r2 = kvS + (d1 + 8) * 12;
        const float4 ka1 = *(const float4*)(r1);
        const float4 kb1 = *(const float4*)(r1 + 4);
        const float2 kc1 = *(const float2*)(r1 + 8);
        const float4 ka2 = *(const float4*)(r2);
        const float4 kb2 = *(const float4*)(r2 + 4);
        const float2 kc2 = *(const float2*)(r2 + 8);
        const float ek1[NT] = {ka1.x, ka1.y, ka1.z, ka1.w, kb1.x, kb1.y, kb1.z, kb1.w, kc1.x, kc1.y};
        const float ek2[NT] = {ka2.x, ka2.y, ka2.z, ka2.w, kb2.x, kb2.y, kb2.z, kb2.w, kc2.x, kc2.y};

        const h2* wrow = &wvpS[(pp * 8 + l) * 4];
        const h2 w0 = wrow[0], w1 = wrow[1], w2 = wrow[2], w3 = wrow[3];

        #pragma unroll
        for (int n = 0; n < NT; ++n) {
            // r = 1/(Eq*Ek + 1); s = 1 - 2r (applied post-reduce via C[h])
            float v1 = __builtin_amdgcn_rcpf(fmaf(Eq1, ek1[n], 1.0f));
            float v2 = __builtin_amdgcn_rcpf(fmaf(Eq2, ek2[n], 1.0f));
            h2 rp = pack_h2(v1, v2);
            R[n][0] = dot2acc(rp, w0, R[n][0]);
            R[n][1] = dot2acc(rp, w1, R[n][1]);
            R[n][2] = dot2acc(rp, w2, R[n][2]);
            R[n][3] = dot2acc(rp, w3, R[n][3]);
        }
    }

    // ---- reduce-scatter R: lane ends with Rh[n] for head h = l&3 ----
    const bool myb0 = (l & 1) != 0;
    const bool myb1 = (l & 2) != 0;
    float lh[NT];
    #pragma unroll
    for (int n = 0; n < NT; ++n) {
        float L0 = R[n][0], L1 = R[n][1];
        float L2 = R[n][2], L3 = R[n][3];
        L0 += __shfl_xor(L0, 4);
        L1 += __shfl_xor(L1, 4);
        L2 += __shfl_xor(L2, 4);
        L3 += __shfl_xor(L3, 4);
        float m0 = myb1 ? L2 : L0, m1 = myb1 ? L3 : L1;
        float t0 = myb1 ? L0 : L2, t1 = myb1 ? L1 : L3;
        m0 += __shfl_xor(t0, 2);
        m1 += __shfl_xor(t1, 2);
        float mm = myb0 ? m1 : m0, tt = myb0 ? m0 : m1;
        lh[n] = mm + __shfl_xor(tt, 1);
    }

    // logits for this lane's head: lh[n] = C[h] - 2*Rh[n]
    {
        const float4 Call = *(const float4*)(ws + WS_C);
        const float Ch = myb0 ? (myb1 ? Call.w : Call.y)
                              : (myb1 ? Call.z : Call.x);
        #pragma unroll
        for (int n = 0; n < NT; ++n) lh[n] = fmaf(-2.0f, lh[n], Ch);
    }

    // ---- per-lane softmax (head l&3); wn[n] = mean_h attn ----
    float m = lh[0];
    #pragma unroll
    for (int n = 1; n < NT; ++n) m = fmaxf(m, lh[n]);
    float e[NT];
    float ssum = 0.0f;
    #pragma unroll
    for (int n = 0; n < NT; ++n) {
        e[n] = __expf(lh[n] - m);
        ssum += e[n];
    }
    const float inv = 0.25f * __builtin_amdgcn_rcpf(ssum);
    float wn[NT];
    #pragma unroll
    for (int n = 0; n < NT; ++n) {
        float v = e[n] * inv;
        v += __shfl_xor(v, 1);
        v += __shfl_xor(v, 2);
        wn[n] = v;
    }

    // ---- style + store; tokens from LDS (banks 4l..4l+3, conflict-free) ----
    float4* ob = (float4*)(out + (size_t)pos * TD);
    const float4* t4 = (const float4*)tokS;
    #pragma unroll
    for (int jj = 0; jj < 3; ++jj) {
        const int d4 = l + 8 * jj;
        float4 o = make_float4(0.f, 0.f, 0.f, 0.f);
        #pragma unroll
        for (int n = 0; n < NT; ++n) {
            float4 t = t4[n * (TD / 4) + d4];
            o.x = fmaf(wn[n], t.x, o.x);
            o.y = fmaf(wn[n], t.y, o.y);
            o.z = fmaf(wn[n], t.z, o.z);
            o.w = fmaf(wn[n], t.w, o.w);
        }
        ob[d4] = o;
    }
}

extern "C" void kernel_launch(void* const* d_in, const int* in_sizes, int n_in,
                              void* d_out, int out_size, void* d_ws, size_t ws_size,
                              hipStream_t stream) {
    const float* ref_emb = (const float*)d_in[0];
    const float* tokens  = (const float*)d_in[1];
    const float* Wq      = (const float*)d_in[2];
    const float* Wk      = (const float*)d_in[3];
    const float* Wv      = (const float*)d_in[4];
    float* out = (float*)d_out;

    gst_prep<<<48, 256, 0, stream>>>(tokens, Wq, Wk, Wv, (char*)d_ws);
    gst_main<<<NPOS / PPB, TPB, 0, stream>>>(ref_emb, tokens,
                                             (const char*)d_ws, out);
}

// Round 23
// 36.670 us; speedup vs baseline: 1.1331x; 1.1331x over previous
//
#include <hip/hip_runtime.h>
#include <rocwmma/rocwmma.hpp>
#include <cstddef>

#define NT 10            // NUM_TOKENS
#define TD 96            // TOKEN_DIM == REF_DIM
#define NH 4             // NUM_HEADS
#define NPOS (32 * 2048) // B*T positions
#define TPB 256
#define PPB 32           // positions per block; 8 lanes/pos in s-phase
#define LDQ 104          // padded f16 leading dim for xS and eqS

// workspace layout (bytes)
#define WS_WQ 0          // f16 wq16[96][96] row-major (18432 B) -> wmma B
#define WS_KV2 18432     // float Ek[96][12]: e^{2 tanh(tok.Wk)}, pad 2 (4608 B)
#define WS_WVP 23040     // h2 wvp[6][8][4]: (Wv[h][16pp+l], Wv[h][16pp+8+l]) (768 B)
#define WS_C 23808       // float C[4]: C[h] = sum_d Wv[h][d] (16 B)
#define WS_BYTES 23824

typedef _Float16 h2 __attribute__((ext_vector_type(2)));

__device__ __forceinline__ h2 pack_h2(float a, float b) {
    return __builtin_bit_cast(h2, __builtin_amdgcn_cvt_pkrtz(a, b));
}

__device__ __forceinline__ float fast_tanh(float x) {
    // tanh(x) = 1 - 2/(exp(2x)+1); exact limits at +/-inf, ~1e-6 rel error
    float e = __expf(2.0f * x);
    return 1.0f - 2.0f * __builtin_amdgcn_rcpf(e + 1.0f);
}

__device__ __forceinline__ float dot2acc(h2 a, h2 b, float c) {
#if __has_builtin(__builtin_amdgcn_fdot2)
    return __builtin_amdgcn_fdot2(a, b, c, false);
#else
    c = fmaf((float)a[0], (float)b[0], c);
    return fmaf((float)a[1], (float)b[1], c);
#endif
}

// ---- prep: 48 blocks; block b owns d-slice [2b, 2b+2); block 0 also wvp/C ----
__global__ __launch_bounds__(256) void gst_prep(
    const float* __restrict__ tokens,
    const float* __restrict__ Wq,
    const float* __restrict__ Wk,
    const float* __restrict__ Wv,
    char* __restrict__ ws)
{
    h2* wqH = (h2*)(ws + WS_WQ);
    float* kv2 = (float*)(ws + WS_KV2);
    h2* wvp = (h2*)(ws + WS_WVP);
    float* Cws = (float*)(ws + WS_C);
    const int b = blockIdx.x;
    const int tid = threadIdx.x;

    // Wq rows -> f16 (2 rows x 48 pairs); [96][48] h2 == [96][96] f16 row-major
    if (tid < 2 * (TD / 2)) {
        int r = 2 * b + tid / (TD / 2);
        int c = tid % (TD / 2);
        float2 f = ((const float2*)(Wq + r * TD))[c];
        wqH[r * (TD / 2) + c] = pack_h2(f.x, f.y);
    }
    // Ek[d][n] = exp(2 * tanh(tokens[n] . Wk[d]))   (exp-form of tanh addition)
    if (tid < 2 * NT) {
        int d = 2 * b + tid / NT;
        int n = tid % NT;
        const float4* tr = (const float4*)(tokens + n * TD);
        const float4* wr = (const float4*)(Wk + d * TD);
        float acc = 0.0f;
        #pragma unroll
        for (int j = 0; j < TD / 4; ++j) {
            float4 a = tr[j];
            float4 w = wr[j];
            acc = fmaf(a.x, w.x, acc);
            acc = fmaf(a.y, w.y, acc);
            acc = fmaf(a.z, w.z, acc);
            acc = fmaf(a.w, w.w, acc);
        }
        kv2[d * 12 + n] = __expf(2.0f * fast_tanh(acc));
    }
    if (tid < 2 * 2) { // zero the pad
        int d = 2 * b + (tid >> 1);
        kv2[d * 12 + 10 + (tid & 1)] = 0.0f;
    }
    // wvp pairs (block 0): 192 items
    if (b == 0 && tid < 192) {
        int pp = tid >> 5;
        int l = (tid >> 2) & 7;
        int h = tid & 3;
        wvp[(pp * 8 + l) * 4 + h] =
            pack_h2(Wv[h * TD + 16 * pp + l], Wv[h * TD + 16 * pp + 8 + l]);
    }
    // C[h] = sum_d Wv[h][d] (block 0, threads 224..227)
    if (b == 0 && tid >= 224 && tid < 224 + NH) {
        int h = tid - 224;
        float c = 0.0f;
        for (int d = 0; d < TD; ++d) c += Wv[h * TD + d];
        Cws[h] = c;
    }
}

// ---- main: rocWMMA q-projection -> Eq f16; xS region reused for tokens so
//      the style phase reads LDS instead of hammering L1 ----
__global__ __launch_bounds__(TPB, 6) void gst_main(
    const float* __restrict__ ref_emb,
    const float* __restrict__ tokens,
    const char* __restrict__ ws,
    float* __restrict__ out)
{
    __shared__ __align__(16) _Float16 xS[PPB * LDQ];  // 6656 B; later tokS f32
    __shared__ __align__(16) _Float16 eqS[PPB * LDQ]; // 6656 B: Eq = e^{2 tanh q}
    __shared__ __align__(16) float kvS[TD * 12];      // 4608 B: Ek
    __shared__ __align__(16) h2 wvpS[6 * 8 * 4];      //  768 B  (total 18688)

    const int tid = threadIdx.x;
    const int P0 = blockIdx.x * PPB;

    // tokens -> registers early (written to LDS after the wmma A-frag loads)
    float4 tokReg;
    if (tid < NT * TD / 4) tokReg = ((const float4*)tokens)[tid];

    // ---- stage x -> LDS f16 + kv/wvp -> LDS, all upfront ----
    {
        const float4* src = (const float4*)(ref_emb + (size_t)P0 * TD);
        #pragma unroll
        for (int it = 0; it < 3; ++it) {
            int t = tid + it * TPB;
            int row = t / (TD / 4);
            int c4 = t - row * (TD / 4);
            float4 v = src[t];
            h2* dst = (h2*)(xS + row * LDQ + c4 * 4);
            dst[0] = pack_h2(v.x, v.y);
            dst[1] = pack_h2(v.z, v.w);
        }
        const float4* sKV = (const float4*)(ws + WS_KV2); // 288 float4
        float4* dKV = (float4*)kvS;
        dKV[tid] = sKV[tid];
        if (tid < 32) dKV[256 + tid] = sKV[256 + tid];
        const float4* sWV = (const float4*)(ws + WS_WVP); // 48 float4
        float4* dWV = (float4*)wvpS;
        if (tid >= 64 && tid < 112) dWV[tid - 64] = sWV[tid - 64];
    }
    __syncthreads();

    // ---- MFMA q phase via rocWMMA; Eq stored f16 by hand (m89 acc mapping:
    //      x[e] -> row = 4*(lane>>4)+e, col = lane&15) ----
    {
        using namespace rocwmma;
        const int lane = tid & 63;
        const int wid = tid >> 6;
        const int ph = wid >> 1;
        const int dh = wid & 1;
        const int arow = lane & 15;
        const int kgrp = lane >> 4;

        fragment<matrix_a, 16, 16, 16, float16_t, row_major> fa[6];
        #pragma unroll
        for (int kb = 0; kb < 6; ++kb)
            load_matrix_sync(fa[kb],
                (const float16_t*)(xS + ph * 16 * LDQ + kb * 16), LDQ);

        __syncthreads(); // all waves' A-frag loads done: xS is now dead

        // overwrite xS region with tokens (f32): style reads LDS, not L1
        if (tid < NT * TD / 4) ((float4*)xS)[tid] = tokReg;

        const float16_t* wq16 = (const float16_t*)(ws + WS_WQ);
        fragment<accumulator, 16, 16, 16, float> fc[3];
        #pragma unroll
        for (int t = 0; t < 3; ++t) {
            fill_fragment(fc[t], 0.0f);
            #pragma unroll
            for (int kb = 0; kb < 6; ++kb) {
                fragment<matrix_b, 16, 16, 16, float16_t, col_major> fb;
                load_matrix_sync(fb, wq16 + (dh * 3 + t) * 16 * TD + kb * 16, TD);
                mma_sync(fc[t], fa[kb], fb, fc[t]);
            }
        }
        #pragma unroll
        for (int t = 0; t < 3; ++t) {
            const int d = dh * 48 + t * 16 + arow;
            #pragma unroll
            for (int e = 0; e < 4; ++e) {
                const int p = ph * 16 + kgrp * 4 + e;
                eqS[p * LDQ + d] = (_Float16)__expf(2.0f * fast_tanh(fc[t].x[e]));
            }
        }
    }
    __syncthreads();

    const float* tokS = (const float*)xS; // [10][96] f32

    // ---- s-phase (exp form): 8 lanes/pos, lane owns d-pair {16pp+l, +8} ----
    const int prow = tid >> 3;
    const int pos = P0 + prow;
    const int l = tid & 7;
    const _Float16* eqrow = eqS + prow * LDQ;

    float R[NT][NH]; // R[n][h] = sum_d r(n,d) * wv(h,d); logit = C - 2R
    #pragma unroll
    for (int n = 0; n < NT; ++n)
        #pragma unroll
        for (int h = 0; h < NH; ++h) R[n][h] = 0.0f;

    #pragma unroll
    for (int pp = 0; pp < 6; ++pp) {
        const int d1 = 16 * pp + l;
        const float Eq1 = (float)eqrow[d1];
        const float Eq2 = (float)eqrow[d1 + 8];

        const float* r1 = kvS + d1 * 12;
        const float* r2 = kvS + (d1 + 8) * 12;
        const float4 ka1 = *(const float4*)(r1);
        const float4 kb1 = *(const float4*)(r1 + 4);
        const float2 kc1 = *(const float2*)(r1 + 8);
        const float4 ka2 = *(const float4*)(r2);
        const float4 kb2 = *(const float4*)(r2 + 4);
        const float2 kc2 = *(const float2*)(r2 + 8);
        const float ek1[NT] = {ka1.x, ka1.y, ka1.z, ka1.w, kb1.x, kb1.y, kb1.z, kb1.w, kc1.x, kc1.y};
        const float ek2[NT] = {ka2.x, ka2.y, ka2.z, ka2.w, kb2.x, kb2.y, kb2.z, kb2.w, kc2.x, kc2.y};

        const h2* wrow = &wvpS[(pp * 8 + l) * 4];
        const h2 w0 = wrow[0], w1 = wrow[1], w2 = wrow[2], w3 = wrow[3];

        #pragma unroll
        for (int n = 0; n < NT; ++n) {
            // r = 1/(Eq*Ek + 1); s = 1 - 2r (applied post-reduce via C[h])
            float v1 = __builtin_amdgcn_rcpf(fmaf(Eq1, ek1[n], 1.0f));
            float v2 = __builtin_amdgcn_rcpf(fmaf(Eq2, ek2[n], 1.0f));
            h2 rp = pack_h2(v1, v2);
            R[n][0] = dot2acc(rp, w0, R[n][0]);
            R[n][1] = dot2acc(rp, w1, R[n][1]);
            R[n][2] = dot2acc(rp, w2, R[n][2]);
            R[n][3] = dot2acc(rp, w3, R[n][3]);
        }
    }

    // ---- reduce-scatter R: lane ends with Rh[n] for head h = l&3 ----
    const bool myb0 = (l & 1) != 0;
    const bool myb1 = (l & 2) != 0;
    float lh[NT];
    #pragma unroll
    for (int n = 0; n < NT; ++n) {
        float L0 = R[n][0], L1 = R[n][1];
        float L2 = R[n][2], L3 = R[n][3];
        L0 += __shfl_xor(L0, 4);
        L1 += __shfl_xor(L1, 4);
        L2 += __shfl_xor(L2, 4);
        L3 += __shfl_xor(L3, 4);
        float m0 = myb1 ? L2 : L0, m1 = myb1 ? L3 : L1;
        float t0 = myb1 ? L0 : L2, t1 = myb1 ? L1 : L3;
        m0 += __shfl_xor(t0, 2);
        m1 += __shfl_xor(t1, 2);
        float mm = myb0 ? m1 : m0, tt = myb0 ? m0 : m1;
        lh[n] = mm + __shfl_xor(tt, 1);
    }

    // logits for this lane's head: lh[n] = C[h] - 2*Rh[n]
    {
        const float4 Call = *(const float4*)(ws + WS_C);
        const float Ch = myb0 ? (myb1 ? Call.w : Call.y)
                              : (myb1 ? Call.z : Call.x);
        #pragma unroll
        for (int n = 0; n < NT; ++n) lh[n] = fmaf(-2.0f, lh[n], Ch);
    }

    // ---- per-lane softmax (head l&3); wn[n] = mean_h attn ----
    float m = lh[0];
    #pragma unroll
    for (int n = 1; n < NT; ++n) m = fmaxf(m, lh[n]);
    float e[NT];
    float ssum = 0.0f;
    #pragma unroll
    for (int n = 0; n < NT; ++n) {
        e[n] = __expf(lh[n] - m);
        ssum += e[n];
    }
    const float inv = 0.25f * __builtin_amdgcn_rcpf(ssum);
    float wn[NT];
    #pragma unroll
    for (int n = 0; n < NT; ++n) {
        float v = e[n] * inv;
        v += __shfl_xor(v, 1);
        v += __shfl_xor(v, 2);
        wn[n] = v;
    }

    // ---- style + store; tokens from LDS (banks 4l..4l+3, conflict-free) ----
    float4* ob = (float4*)(out + (size_t)pos * TD);
    const float4* t4 = (const float4*)tokS;
    #pragma unroll
    for (int jj = 0; jj < 3; ++jj) {
        const int d4 = l + 8 * jj;
        float4 o = make_float4(0.f, 0.f, 0.f, 0.f);
        #pragma unroll
        for (int n = 0; n < NT; ++n) {
            float4 t = t4[n * (TD / 4) + d4];
            o.x = fmaf(wn[n], t.x, o.x);
            o.y = fmaf(wn[n], t.y, o.y);
            o.z = fmaf(wn[n], t.z, o.z);
            o.w = fmaf(wn[n], t.w, o.w);
        }
        ob[d4] = o;
    }
}

extern "C" void kernel_launch(void* const* d_in, const int* in_sizes, int n_in,
                              void* d_out, int out_size, void* d_ws, size_t ws_size,
                              hipStream_t stream) {
    const float* ref_emb = (const float*)d_in[0];
    const float* tokens  = (const float*)d_in[1];
    const float* Wq      = (const float*)d_in[2];
    const float* Wk      = (const float*)d_in[3];
    const float* Wv      = (const float*)d_in[4];
    float* out = (float*)d_out;

    gst_prep<<<48, 256, 0, stream>>>(tokens, Wq, Wk, Wv, (char*)d_ws);
    gst_main<<<NPOS / PPB, TPB, 0, stream>>>(ref_emb, tokens,
                                             (const char*)d_ws, out);
}